// Round 26
// baseline (137.029 us; speedup 1.0000x reference)
//
#include <hip/hip_runtime.h>
#include <hip/hip_bf16.h>

#define B_  2
#define S_  2048
#define D_  1024
#define H_  16
#define HD_ 64
#define M_  (B_*S_)   // 4096 rows of x

typedef __attribute__((ext_vector_type(8))) short short8;
typedef __attribute__((ext_vector_type(4))) float f32x4;

#define MFMA16(a, b, c) __builtin_amdgcn_mfma_f32_16x16x32_bf16((a), (b), (c), 0, 0, 0)

static __device__ inline short f2bf(float f) {
    union { float f; unsigned u; } v; v.f = f;
    unsigned r = v.u + 0x7FFFu + ((v.u >> 16) & 1u);   // round-to-nearest-even
    return (short)(r >> 16);
}

static __device__ __forceinline__ float fexp2(float x) {   // v_exp_f32 = 2^x
    float r;
    asm volatile("v_exp_f32 %0, %1\n\ts_nop 1" : "=v"(r) : "v"(x));
    return r;
}

static __device__ __forceinline__ unsigned cvt_pk_bf16(float lo, float hi) {
    unsigned r;
    asm volatile("v_cvt_pk_bf16_f32 %0, %1, %2" : "=v"(r) : "v"(lo), "v"(hi));
    return r;
}

static __device__ __forceinline__ void gl_lds16(const short* g, short* l) {
    __builtin_amdgcn_global_load_lds(
        (const __attribute__((address_space(1))) void*)g,
        (__attribute__((address_space(3))) void*)l, 16, 0, 0);
}

// ------- fused prep: z<4 -> transpose W_z to bf16 [N][K]; z==4 -> cvt x ----
__global__ void prep_kernel(const float* __restrict__ x,
                            const float* __restrict__ Wq, const float* __restrict__ Wk,
                            const float* __restrict__ Wv, const float* __restrict__ Wo,
                            short* __restrict__ xb,
                            short* __restrict__ Wqkvt, short* __restrict__ Wot) {
    int z = blockIdx.z;
    if (z == 4) {                                      // x fp32 -> bf16 (4 float4/thread)
        int bid = blockIdx.y * 32 + blockIdx.x;
        int base = bid * 1024 + threadIdx.x;
#pragma unroll
        for (int it = 0; it < 4; ++it) {
            int i = base + it * 256;
            float4 v = ((const float4*)x)[i];
            short4 o;
            o.x = f2bf(v.x); o.y = f2bf(v.y); o.z = f2bf(v.z); o.w = f2bf(v.w);
            ((short4*)xb)[i] = o;
        }
        return;
    }
    __shared__ float tile[32][33];
    const float* W = (z == 0) ? Wq : (z == 1) ? Wk : (z == 2) ? Wv : Wo;
    short* Wt = (z == 3) ? Wot : (Wqkvt + ((size_t)z << 20));
    int tx = threadIdx.x & 31, ty = threadIdx.x >> 5;   // 32x8
    int n0 = blockIdx.x * 32, k0 = blockIdx.y * 32;
#pragma unroll
    for (int i = 0; i < 4; ++i)
        tile[ty + 8 * i][tx] = W[(size_t)(k0 + ty + 8 * i) * D_ + n0 + tx];
    __syncthreads();
#pragma unroll
    for (int i = 0; i < 4; ++i)
        Wt[(size_t)(n0 + ty + 8 * i) * D_ + k0 + tx] = f2bf(tile[tx][ty + 8 * i]);
}

// ---------------- fused QKV GEMM: barrier-free per-wave pipelines ----------
// C[M][3072] = A[M][1024] * Bt[3072][1024]^T.  Block = 4 waves covering a
// 128x128 tile as 2x2 of PER-WAVE 64x64 tiles.  Each wave stages its OWN
// A/B 64x32 panels into PRIVATE LDS (16 KB/wave) via global_load_lds, which
// is tracked by the issuing wave's vmcnt -> ZERO barriers; counted vmcnt(8)
// keeps a 2-deep pipeline per wave (8 waves/CU all independent).
// WAR on buffer reuse closed by lgkmcnt(0) after the fragment ds_reads.
// Chunk bijection (r14-proven, conflict-free ds_read_b128):
//   chunk(row,s) = ((row>>3)<<5) | ((s^(row&3))<<3) | (row&7)
// XCD-aware: XCD (bid&7) owns 3 bn-columns.  Epilogue: Q,K [b][h][s][hd];
// V^T [b][h][hd][s].
__global__ __launch_bounds__(256) void gemm_qkv(const short* __restrict__ A,
                                                const short* __restrict__ Bt,
                                                short* __restrict__ out) {
    __shared__ __align__(16) short lds[4][2][2][2048];  // [wave][buf][mat][4KB]
    const int NBX = 3;                                 // 24 bn-columns / 8 XCDs
    int X = blockIdx.x & 7, t0 = blockIdx.x >> 3;
    int bm = t0 / NBX, bn = X * NBX + t0 % NBX;
    int tid = threadIdx.x, l = tid & 63, w = tid >> 6;
    int lhi = l >> 4, llo = l & 15;
    int wm = w >> 1, wn = w & 1;

    f32x4 acc[4][4];
#pragma unroll
    for (int m = 0; m < 4; ++m)
#pragma unroll
        for (int n = 0; n < 4; ++n) acc[m][n] = (f32x4){0.f, 0.f, 0.f, 0.f};

    const short* Aw = A + (size_t)(bm * 128 + wm * 64) * 1024;
    const short* Bw = Bt + (size_t)(bn * 128 + wn * 64) * 1024;

    // per-lane staging decode: 4 chunks per matrix, c = 64*i + l
    int rr[4], ss[4];
#pragma unroll
    for (int i = 0; i < 4; ++i) {
        int c = 64 * i + l;
        rr[i] = ((c >> 5) << 3) | (c & 7);
        ss[i] = ((c >> 3) & 3) ^ (rr[i] & 3);
    }

    auto stage = [&](int buf, int k0) {                // 8 gl_lds, this wave only
#pragma unroll
        for (int i = 0; i < 4; ++i)
            gl_lds16(Aw + (size_t)rr[i] * 1024 + k0 + ss[i] * 8,
                     &lds[w][buf][0][(64 * i + l) * 8]);
#pragma unroll
        for (int i = 0; i < 4; ++i)
            gl_lds16(Bw + (size_t)rr[i] * 1024 + k0 + ss[i] * 8,
                     &lds[w][buf][1][(64 * i + l) * 8]);
    };

    // fragment chunk indices (A and B use the same row formula f*16+llo)
    int ci[4];
#pragma unroll
    for (int f = 0; f < 4; ++f) {
        int row = f * 16 + llo;
        ci[f] = ((row >> 3) << 5) | (((lhi ^ row) & 3) << 3) | (row & 7);
    }

    stage(0, 0);
    stage(1, 32);
#pragma unroll 1
    for (int t = 0; t < 32; ++t) {
        if (t < 31) { asm volatile("s_waitcnt vmcnt(8)" ::: "memory"); }
        else        { asm volatile("s_waitcnt vmcnt(0)" ::: "memory"); }
        int cur = t & 1;
        short8 af[4], bf[4];
#pragma unroll
        for (int m = 0; m < 4; ++m) af[m] = *(const short8*)&lds[w][cur][0][ci[m] * 8];
#pragma unroll
        for (int n = 0; n < 4; ++n) bf[n] = *(const short8*)&lds[w][cur][1][ci[n] * 8];
        asm volatile("s_waitcnt lgkmcnt(0)" ::: "memory");   // reads done before rebuffer
        if (t + 2 < 32) stage(cur, (t + 2) * 32);
#pragma unroll
        for (int m = 0; m < 4; ++m)
#pragma unroll
            for (int n = 0; n < 4; ++n)
                acc[m][n] = MFMA16(af[m], bf[n], acc[m][n]);
    }

    int rowb = bm * 128 + wm * 64, colb = bn * 128 + wn * 64;
#pragma unroll
    for (int m = 0; m < 4; ++m) {
#pragma unroll
        for (int n = 0; n < 4; ++n) {
            int col = colb + n * 16 + llo;
#pragma unroll
            for (int j = 0; j < 4; ++j) {
                int row = rowb + m * 16 + lhi * 4 + j;
                float v = acc[m][n][j];
                int proj = col >> 10, n1 = col & 1023;
                int h = n1 >> 6, hd = n1 & 63;
                int b = row >> 11, s = row & 2047;
                size_t off;
                if (proj == 0)
                    off = ((size_t)(b * 16 + h) * 2048 + s) * 64 + hd;
                else if (proj == 1)
                    off = (size_t)M_ * D_ + ((size_t)(b * 16 + h) * 2048 + s) * 64 + hd;
                else
                    off = (size_t)2 * M_ * D_ + ((size_t)(b * 16 + h) * 64 + hd) * 2048 + s;
                out[off] = f2bf(v);
            }
        }
    }
}

// ---------------- out-proj GEMM: 64x128, double-buffered (r16-proven) ------
__global__ __launch_bounds__(256, 6) void gemm_out(const short* __restrict__ A,
                                                   const short* __restrict__ Bt,
                                                   const float* __restrict__ bias,
                                                   float* __restrict__ out) {
    __shared__ __align__(16) short Asm[2][64 * 32];
    __shared__ __align__(16) short Bsm[2][128 * 32];
    int bn = blockIdx.x & 7, bm = blockIdx.x >> 3;
    int tid = threadIdx.x, l = tid & 63, w = tid >> 6;
    int lhi = l >> 4, llo = l & 15;

    f32x4 acc[4][2];
#pragma unroll
    for (int m = 0; m < 4; ++m)
#pragma unroll
        for (int n = 0; n < 2; ++n) acc[m][n] = (f32x4){0.f, 0.f, 0.f, 0.f};

    const short* Ag = A + (size_t)(bm * 64) * 1024;
    const short* Bg = Bt + (size_t)(bn * 128) * 1024;
    int ca = tid;
    int ra = ((ca >> 5) << 3) | (ca & 7), sa = ((ca >> 3) & 3) ^ (ra & 3);
    int cb0 = tid, cb1 = tid + 256;
    int rb0 = ((cb0 >> 5) << 3) | (cb0 & 7), sb0 = ((cb0 >> 3) & 3) ^ (rb0 & 3);
    int rb1 = ((cb1 >> 5) << 3) | (cb1 & 7), sb1 = ((cb1 >> 3) & 3) ^ (rb1 & 3);

    auto stage = [&](int buf, int k0) {
        gl_lds16(Ag + (size_t)ra * 1024 + k0 + sa * 8, &Asm[buf][ca * 8]);
        gl_lds16(Bg + (size_t)rb0 * 1024 + k0 + sb0 * 8, &Bsm[buf][cb0 * 8]);
        gl_lds16(Bg + (size_t)rb1 * 1024 + k0 + sb1 * 8, &Bsm[buf][cb1 * 8]);
    };

    int cia[4], cib[2];
#pragma unroll
    for (int m = 0; m < 4; ++m) {
        int row = m * 16 + llo;
        cia[m] = ((row >> 3) << 5) | (((lhi ^ row) & 3) << 3) | (row & 7);
    }
#pragma unroll
    for (int n = 0; n < 2; ++n) {
        int row = w * 32 + n * 16 + llo;
        cib[n] = ((row >> 3) << 5) | (((lhi ^ row) & 3) << 3) | (row & 7);
    }

    stage(0, 0);
    for (int i = 0; i < 32; ++i) {
        asm volatile("s_waitcnt vmcnt(0)" ::: "memory");
        __builtin_amdgcn_s_barrier();
        asm volatile("" ::: "memory");
        if (i + 1 < 32) stage((i + 1) & 1, (i + 1) * 32);
        int cur = i & 1;
        short8 af[4], bf[2];
#pragma unroll
        for (int m = 0; m < 4; ++m) af[m] = *(const short8*)&Asm[cur][cia[m] * 8];
#pragma unroll
        for (int n = 0; n < 2; ++n) bf[n] = *(const short8*)&Bsm[cur][cib[n] * 8];
#pragma unroll
        for (int m = 0; m < 4; ++m)
#pragma unroll
            for (int n = 0; n < 2; ++n)
                acc[m][n] = MFMA16(af[m], bf[n], acc[m][n]);
    }

    int rowb = bm * 64, colb = bn * 128 + w * 32;
#pragma unroll
    for (int m = 0; m < 4; ++m)
#pragma unroll
        for (int n = 0; n < 2; ++n) {
            int col = colb + n * 16 + llo;
#pragma unroll
            for (int j = 0; j < 4; ++j) {
                int row = rowb + m * 16 + lhi * 4 + j;
                out[(size_t)row * 1024 + col] = acc[m][n][j] + bias[col];
            }
        }
}

// ---------------- causal flash attention, k-tile = 128 (r25-proven) --------
__global__ __launch_bounds__(512) void attn_kernel(const short* __restrict__ Q,
                                                   const short* __restrict__ Kg,
                                                   const short* __restrict__ Vt,
                                                   short* __restrict__ ctx) {
    __shared__ __align__(16) char kvbuf[2][32768];   // per buf: K 16KB | V 16KB
    __shared__ __align__(16) char plds[8][2][2048];  // per-wave 2 x (16x64) P
    int tid = threadIdx.x, w = tid >> 6, l = tid & 63;
    int lhi = l >> 4, llo = l & 15;
    int bh = blockIdx.x & 31, qp = blockIdx.x >> 5;  // qp 0..7
    int b = bh >> 4, h = bh & 15;
    char* pb0 = plds[w][0];
    char* pb1 = plds[w][1];

    const short* Qh = Q + (size_t)bh * S_ * HD_;
    const short* Kh = Kg + (size_t)bh * S_ * HD_;
    const short* Vh = Vt + (size_t)bh * HD_ * S_;

    int qbA = qp, qbB = 15 - qp;
    int NTA = qp + 1;
    const int NT = 17;                               // (qp+1) + (16-qp)

    auto stage = [&](char* buf, int c0) {
#pragma unroll
        for (int i2 = 0; i2 < 2; ++i2) {
            int cc = tid + 512 * i2;                 // 0..1023
            int kr = cc >> 3, ks = (16 * (cc & 7)) ^ ((kr & 7) << 4);
            gl_lds16(Kh + (size_t)(c0 + kr) * HD_ + (ks >> 1), (short*)(buf + cc * 16));
            int vr = cc >> 4, vs = (16 * (cc & 15)) ^ ((vr & 15) << 4);
            gl_lds16(Vh + (size_t)vr * S_ + c0 + (vs >> 1),
                     (short*)(buf + 16384 + cc * 16));
        }
    };

    f32x4 O[4];
#pragma unroll
    for (int n = 0; n < 4; ++n) O[n] = (f32x4){0.f, 0.f, 0.f, 0.f};
    float lpart[4] = {0.f, 0.f, 0.f, 0.f};

    auto writeOut = [&](int qb) {
        int qbs = qb * 128 + w * 16;
#pragma unroll
        for (int j = 0; j < 4; ++j) {
            float ls = lpart[j];
            ls += __shfl_xor(ls, 1);
            ls += __shfl_xor(ls, 2);
            ls += __shfl_xor(ls, 4);
            ls += __shfl_xor(ls, 8);
            float inv = 1.0f / ls;
            int row = qbs + lhi * 4 + j;
            size_t base = ((size_t)(b * S_ + row)) * D_ + h * HD_;
#pragma unroll
            for (int n = 0; n < 4; ++n)
                ctx[base + n * 16 + llo] = f2bf(O[n][j] * inv);
        }
    };

    const float SC = 0.18033688f;                    // 0.125 * log2(e)
    const float M2 = 17.312340f;                     // 12 * log2(e) (fixed max)

    int qbase = qbA * 128 + w * 16;
    short8 aq0 = *(const short8*)(Qh + (size_t)(qbase + llo) * HD_ + 8 * lhi);
    short8 aq1 = *(const short8*)(Qh + (size_t)(qbase + llo) * HD_ + 32 + 8 * lhi);

    stage(kvbuf[0], 0);

    for (int i = 0; i < NT; ++i) {
        asm volatile("s_waitcnt vmcnt(0)" ::: "memory");
        __builtin_amdgcn_s_barrier();
        asm volatile("" ::: "memory");
        int kt = (i < NTA) ? i : i - NTA;
        int c0 = kt * 128;
        if (i + 1 < NT) {
            int ni = i + 1;
            int nkt = (ni < NTA) ? ni : ni - NTA;
            stage(kvbuf[ni & 1], nkt * 128);
        }
        const char* kb = kvbuf[i & 1];
        const char* vb = kb + 16384;

        if (c0 <= qbase + 15) {
            // ---- QK^T: 8 col-blocks of 16 k ----
            f32x4 sc4[8];
#pragma unroll
            for (int cb = 0; cb < 8; ++cb) {
                int row = cb * 16 + llo;
                int sw = (row & 7) << 4;
                short8 kf0 = *(const short8*)(kb + row * 128 + ((16 * lhi) ^ sw));
                short8 kf1 = *(const short8*)(kb + row * 128 + ((64 + 16 * lhi) ^ sw));
                f32x4 z = (f32x4){0.f, 0.f, 0.f, 0.f};
                z = MFMA16(aq0, kf0, z);
                z = MFMA16(aq1, kf1, z);
                sc4[cb] = z;
            }
            // ---- fixed-max softmax, two P half-tiles ----
            bool diag = (c0 + 127 > qbase);          // only the true diagonal tile
#pragma unroll
            for (int j = 0; j < 4; ++j) {
                int qr = qbase + lhi * 4 + j;
                float p[8];
#pragma unroll
                for (int cb = 0; cb < 8; ++cb) {
                    float v = fmaf(sc4[cb][j], SC, -M2);
                    if (diag && (c0 + cb * 16 + llo > qr)) v = -1e30f;
                    p[cb] = fexp2(v);
                }
                lpart[j] += ((p[0] + p[1]) + (p[2] + p[3])) +
                            ((p[4] + p[5]) + (p[6] + p[7]));
                int r = lhi * 4 + j;
                int sw = (r & 7) << 4;
                unsigned pkA = cvt_pk_bf16(p[0], p[1]);
                unsigned pkB = cvt_pk_bf16(p[2], p[3]);
                char* rb = pb0 + r * 128;
                *(short*)(rb + ((2 * llo) ^ sw))      = (short)(pkA);
                *(short*)(rb + ((2 * llo + 32) ^ sw)) = (short)(pkA >> 16);
                *(short*)(rb + ((2 * llo + 64) ^ sw)) = (short)(pkB);
                *(short*)(rb + ((2 * llo + 96) ^ sw)) = (short)(pkB >> 16);
                unsigned pkC = cvt_pk_bf16(p[4], p[5]);
                unsigned pkD = cvt_pk_bf16(p[6], p[7]);
                rb = pb1 + r * 128;
                *(short*)(rb + ((2 * llo) ^ sw))      = (short)(pkC);
                *(short*)(rb + ((2 * llo + 32) ^ sw)) = (short)(pkC >> 16);
                *(short*)(rb + ((2 * llo + 64) ^ sw)) = (short)(pkD);
                *(short*)(rb + ((2 * llo + 96) ^ sw)) = (short)(pkD >> 16);
            }
            // ---- PV: 4 k-chunks of 32 ----
            int swr = (llo & 7) << 4;
            short8 pa[4];
            pa[0] = *(const short8*)(pb0 + llo * 128 + ((16 * lhi) ^ swr));
            pa[1] = *(const short8*)(pb0 + llo * 128 + ((64 + 16 * lhi) ^ swr));
            pa[2] = *(const short8*)(pb1 + llo * 128 + ((16 * lhi) ^ swr));
            pa[3] = *(const short8*)(pb1 + llo * 128 + ((64 + 16 * lhi) ^ swr));
#pragma unroll
            for (int n = 0; n < 4; ++n) {
                int vrow = n * 16 + llo;
                int vsw = (vrow & 15) << 4;
#pragma unroll
                for (int kc = 0; kc < 4; ++kc) {
                    short8 vf = *(const short8*)(vb + vrow * 256 +
                                                 ((kc * 64 + 16 * lhi) ^ vsw));
                    O[n] = MFMA16(pa[kc], vf, O[n]);
                }
            }
        }

        if (i == NTA - 1) {                          // phase A done
            writeOut(qbA);
#pragma unroll
            for (int n = 0; n < 4; ++n) O[n] = (f32x4){0.f, 0.f, 0.f, 0.f};
            lpart[0] = lpart[1] = lpart[2] = lpart[3] = 0.f;
            qbase = qbB * 128 + w * 16;
            aq0 = *(const short8*)(Qh + (size_t)(qbase + llo) * HD_ + 8 * lhi);
            aq1 = *(const short8*)(Qh + (size_t)(qbase + llo) * HD_ + 32 + 8 * lhi);
        }
    }
    writeOut(qbB);
}

extern "C" void kernel_launch(void* const* d_in, const int* in_sizes, int n_in,
                              void* d_out, int out_size, void* d_ws, size_t ws_size,
                              hipStream_t stream) {
    const float* x  = (const float*)d_in[0];
    const float* Wq = (const float*)d_in[1];
    const float* Wk = (const float*)d_in[2];
    const float* Wv = (const float*)d_in[3];
    const float* Wo = (const float*)d_in[4];
    const float* bo = (const float*)d_in[5];
    float* out = (float*)d_out;

    char* ws = (char*)d_ws;
    short* xb    = (short*)(ws);                       // 8 MB (reused as ctx later)
    short* Wqkvt = (short*)(ws + (size_t)(8 << 20));   // 6 MB: [3072][1024] bf16
    short* Wot   = (short*)(ws + (size_t)(14 << 20));  // 2 MB
    short* Qb    = (short*)(ws + (size_t)(16 << 20));  // 8 MB each
    short* Kb    = Qb + (size_t)M_ * D_;
    short* Vtb   = Qb + (size_t)2 * M_ * D_;
    short* ctx   = xb;                                 // alias: xb dead after QKV GEMM

    prep_kernel<<<dim3(32, 32, 5), 256, 0, stream>>>(x, Wq, Wk, Wv, Wo, xb, Wqkvt, Wot);
    gemm_qkv<<<768, 256, 0, stream>>>(xb, Wqkvt, Qb);                      // fused QKV
    attn_kernel<<<256, 512, 0, stream>>>(Qb, Kb, Vtb, ctx);
    gemm_out<<<512, 256, 0, stream>>>(ctx, Wot, bo, out);                  // out-proj
}

// Round 27
// 131.043 us; speedup vs baseline: 1.0457x; 1.0457x over previous
//
#include <hip/hip_runtime.h>
#include <hip/hip_bf16.h>

#define B_  2
#define S_  2048
#define D_  1024
#define H_  16
#define HD_ 64
#define M_  (B_*S_)   // 4096 rows of x

typedef __attribute__((ext_vector_type(8))) short short8;
typedef __attribute__((ext_vector_type(4))) float f32x4;

#define MFMA16(a, b, c) __builtin_amdgcn_mfma_f32_16x16x32_bf16((a), (b), (c), 0, 0, 0)

static __device__ inline short f2bf(float f) {
    union { float f; unsigned u; } v; v.f = f;
    unsigned r = v.u + 0x7FFFu + ((v.u >> 16) & 1u);   // round-to-nearest-even
    return (short)(r >> 16);
}

static __device__ __forceinline__ float fexp2(float x) {   // v_exp_f32 = 2^x
    float r;
    asm volatile("v_exp_f32 %0, %1\n\ts_nop 1" : "=v"(r) : "v"(x));
    return r;
}

static __device__ __forceinline__ unsigned cvt_pk_bf16(float lo, float hi) {
    unsigned r;
    asm volatile("v_cvt_pk_bf16_f32 %0, %1, %2" : "=v"(r) : "v"(lo), "v"(hi));
    return r;
}

static __device__ __forceinline__ void gl_lds16(const short* g, short* l) {
    __builtin_amdgcn_global_load_lds(
        (const __attribute__((address_space(1))) void*)g,
        (__attribute__((address_space(3))) void*)l, 16, 0, 0);
}

// ------- fused prep: z<4 -> transpose W_z to bf16 [N][K]; z==4 -> cvt x ----
// Transpose path fully vectorized: one float4 load + one short4 store/thread.
__global__ void prep_kernel(const float* __restrict__ x,
                            const float* __restrict__ Wq, const float* __restrict__ Wk,
                            const float* __restrict__ Wv, const float* __restrict__ Wo,
                            short* __restrict__ xb,
                            short* __restrict__ Wqkvt, short* __restrict__ Wot) {
    int z = blockIdx.z;
    if (z == 4) {                                      // x fp32 -> bf16 (4 float4/thread)
        int bid = blockIdx.y * 32 + blockIdx.x;
        int base = bid * 1024 + threadIdx.x;
#pragma unroll
        for (int it = 0; it < 4; ++it) {
            int i = base + it * 256;
            float4 v = ((const float4*)x)[i];
            short4 o;
            o.x = f2bf(v.x); o.y = f2bf(v.y); o.z = f2bf(v.z); o.w = f2bf(v.w);
            ((short4*)xb)[i] = o;
        }
        return;
    }
    __shared__ float tile[32][33];
    const float* W = (z == 0) ? Wq : (z == 1) ? Wk : (z == 2) ? Wv : Wo;
    short* Wt = (z == 3) ? Wot : (Wqkvt + ((size_t)z << 20));
    int t8 = threadIdx.x & 7, ty = threadIdx.x >> 3;   // 8 float4-cols x 32 rows
    int n0 = blockIdx.x * 32, k0 = blockIdx.y * 32;
    float4 v = *(const float4*)&W[(size_t)(k0 + ty) * D_ + n0 + t8 * 4];
    tile[ty][t8 * 4 + 0] = v.x;
    tile[ty][t8 * 4 + 1] = v.y;
    tile[ty][t8 * 4 + 2] = v.z;
    tile[ty][t8 * 4 + 3] = v.w;
    __syncthreads();
    short4 o;
    o.x = f2bf(tile[t8 * 4 + 0][ty]);
    o.y = f2bf(tile[t8 * 4 + 1][ty]);
    o.z = f2bf(tile[t8 * 4 + 2][ty]);
    o.w = f2bf(tile[t8 * 4 + 3][ty]);
    *(short4*)&Wt[(size_t)(n0 + ty) * D_ + k0 + t8 * 4] = o;
}

// ---------------- fused QKV GEMM: 128x128, double-buffered (r14/r18-proven) -
// C[M][3072] = A[M][1024] * Bt[3072][1024]^T.  Stage(i+1) issued after the
// top vmcnt(0)+barrier of step i.  LDS chunk bijection (conflict-free):
//   chunk(row,s) = ((row>>3)<<5) | ((s^(row&3))<<3) | (row&7)
// XCD-aware: XCD (bid&7) owns 3 bn-columns (B-panels L2-resident).
// Epilogue: Q,K [b][h][s][hd]; V^T [b][h][hd][s] (plain layout).
__global__ __launch_bounds__(256) void gemm_qkv(const short* __restrict__ A,
                                                const short* __restrict__ Bt,
                                                short* __restrict__ out) {
    __shared__ __align__(16) short Asm[2][128 * 32];
    __shared__ __align__(16) short Bsm[2][128 * 32];
    const int NBX = 3;                                 // 24 bn-columns / 8 XCDs
    int X = blockIdx.x & 7, t = blockIdx.x >> 3;
    int bm = t / NBX, bn = X * NBX + t % NBX;
    int tid = threadIdx.x, l = tid & 63, w = tid >> 6;
    int lhi = l >> 4, llo = l & 15;
    int wm = w >> 1, wn = w & 1;

    f32x4 acc[4][4];
#pragma unroll
    for (int m = 0; m < 4; ++m)
#pragma unroll
        for (int n = 0; n < 4; ++n) acc[m][n] = (f32x4){0.f, 0.f, 0.f, 0.f};

    const short* Ag = A + (size_t)(bm * 128) * 1024;
    const short* Bg = Bt + (size_t)(bn * 128) * 1024;
    int c0 = tid, c1 = 256 + tid;
    int r0 = ((c0 >> 5) << 3) | (c0 & 7), s0 = ((c0 >> 3) & 3) ^ (r0 & 3);
    int r1 = ((c1 >> 5) << 3) | (c1 & 7), s1 = ((c1 >> 3) & 3) ^ (r1 & 3);

    auto stage = [&](int buf, int k0) {
        gl_lds16(Ag + (size_t)r0 * 1024 + k0 + s0 * 8, &Asm[buf][c0 * 8]);
        gl_lds16(Ag + (size_t)r1 * 1024 + k0 + s1 * 8, &Asm[buf][c1 * 8]);
        gl_lds16(Bg + (size_t)r0 * 1024 + k0 + s0 * 8, &Bsm[buf][c0 * 8]);
        gl_lds16(Bg + (size_t)r1 * 1024 + k0 + s1 * 8, &Bsm[buf][c1 * 8]);
    };

    int cia[4], cib[4];
#pragma unroll
    for (int m = 0; m < 4; ++m) {
        int row = wm * 64 + m * 16 + llo;
        cia[m] = ((row >> 3) << 5) | (((lhi ^ row) & 3) << 3) | (row & 7);
    }
#pragma unroll
    for (int n = 0; n < 4; ++n) {
        int row = wn * 64 + n * 16 + llo;
        cib[n] = ((row >> 3) << 5) | (((lhi ^ row) & 3) << 3) | (row & 7);
    }

    stage(0, 0);
    for (int i = 0; i < 32; ++i) {
        asm volatile("s_waitcnt vmcnt(0)" ::: "memory");
        __builtin_amdgcn_s_barrier();
        asm volatile("" ::: "memory");
        if (i + 1 < 32) stage((i + 1) & 1, (i + 1) * 32);
        int cur = i & 1;
        short8 af[4], bf[4];
#pragma unroll
        for (int m = 0; m < 4; ++m) af[m] = *(const short8*)&Asm[cur][cia[m] * 8];
#pragma unroll
        for (int n = 0; n < 4; ++n) bf[n] = *(const short8*)&Bsm[cur][cib[n] * 8];
#pragma unroll
        for (int m = 0; m < 4; ++m)
#pragma unroll
            for (int n = 0; n < 4; ++n)
                acc[m][n] = MFMA16(af[m], bf[n], acc[m][n]);
    }

    int rowb = bm * 128 + wm * 64, colb = bn * 128 + wn * 64;
#pragma unroll
    for (int m = 0; m < 4; ++m) {
#pragma unroll
        for (int n = 0; n < 4; ++n) {
            int col = colb + n * 16 + llo;
#pragma unroll
            for (int j = 0; j < 4; ++j) {
                int row = rowb + m * 16 + lhi * 4 + j;
                float v = acc[m][n][j];
                int proj = col >> 10, n1 = col & 1023;
                int h = n1 >> 6, hd = n1 & 63;
                int b = row >> 11, s = row & 2047;
                size_t off;
                if (proj == 0)
                    off = ((size_t)(b * 16 + h) * 2048 + s) * 64 + hd;
                else if (proj == 1)
                    off = (size_t)M_ * D_ + ((size_t)(b * 16 + h) * 2048 + s) * 64 + hd;
                else
                    off = (size_t)2 * M_ * D_ + ((size_t)(b * 16 + h) * 64 + hd) * 2048 + s;
                out[off] = f2bf(v);
            }
        }
    }
}

// ---------------- out-proj GEMM: 64x128, double-buffered (r16-proven) ------
__global__ __launch_bounds__(256, 6) void gemm_out(const short* __restrict__ A,
                                                   const short* __restrict__ Bt,
                                                   const float* __restrict__ bias,
                                                   float* __restrict__ out) {
    __shared__ __align__(16) short Asm[2][64 * 32];
    __shared__ __align__(16) short Bsm[2][128 * 32];
    int bn = blockIdx.x & 7, bm = blockIdx.x >> 3;
    int tid = threadIdx.x, l = tid & 63, w = tid >> 6;
    int lhi = l >> 4, llo = l & 15;

    f32x4 acc[4][2];
#pragma unroll
    for (int m = 0; m < 4; ++m)
#pragma unroll
        for (int n = 0; n < 2; ++n) acc[m][n] = (f32x4){0.f, 0.f, 0.f, 0.f};

    const short* Ag = A + (size_t)(bm * 64) * 1024;
    const short* Bg = Bt + (size_t)(bn * 128) * 1024;
    int ca = tid;
    int ra = ((ca >> 5) << 3) | (ca & 7), sa = ((ca >> 3) & 3) ^ (ra & 3);
    int cb0 = tid, cb1 = tid + 256;
    int rb0 = ((cb0 >> 5) << 3) | (cb0 & 7), sb0 = ((cb0 >> 3) & 3) ^ (rb0 & 3);
    int rb1 = ((cb1 >> 5) << 3) | (cb1 & 7), sb1 = ((cb1 >> 3) & 3) ^ (rb1 & 3);

    auto stage = [&](int buf, int k0) {
        gl_lds16(Ag + (size_t)ra * 1024 + k0 + sa * 8, &Asm[buf][ca * 8]);
        gl_lds16(Bg + (size_t)rb0 * 1024 + k0 + sb0 * 8, &Bsm[buf][cb0 * 8]);
        gl_lds16(Bg + (size_t)rb1 * 1024 + k0 + sb1 * 8, &Bsm[buf][cb1 * 8]);
    };

    int cia[4], cib[2];
#pragma unroll
    for (int m = 0; m < 4; ++m) {
        int row = m * 16 + llo;
        cia[m] = ((row >> 3) << 5) | (((lhi ^ row) & 3) << 3) | (row & 7);
    }
#pragma unroll
    for (int n = 0; n < 2; ++n) {
        int row = w * 32 + n * 16 + llo;
        cib[n] = ((row >> 3) << 5) | (((lhi ^ row) & 3) << 3) | (row & 7);
    }

    stage(0, 0);
    for (int i = 0; i < 32; ++i) {
        asm volatile("s_waitcnt vmcnt(0)" ::: "memory");
        __builtin_amdgcn_s_barrier();
        asm volatile("" ::: "memory");
        if (i + 1 < 32) stage((i + 1) & 1, (i + 1) * 32);
        int cur = i & 1;
        short8 af[4], bf[2];
#pragma unroll
        for (int m = 0; m < 4; ++m) af[m] = *(const short8*)&Asm[cur][cia[m] * 8];
#pragma unroll
        for (int n = 0; n < 2; ++n) bf[n] = *(const short8*)&Bsm[cur][cib[n] * 8];
#pragma unroll
        for (int m = 0; m < 4; ++m)
#pragma unroll
            for (int n = 0; n < 2; ++n)
                acc[m][n] = MFMA16(af[m], bf[n], acc[m][n]);
    }

    int rowb = bm * 64, colb = bn * 128 + w * 32;
#pragma unroll
    for (int m = 0; m < 4; ++m)
#pragma unroll
        for (int n = 0; n < 2; ++n) {
            int col = colb + n * 16 + llo;
#pragma unroll
            for (int j = 0; j < 4; ++j) {
                int row = rowb + m * 16 + lhi * 4 + j;
                out[(size_t)row * 1024 + col] = acc[m][n][j] + bias[col];
            }
        }
}

// ---------------- causal flash attention, k-tile = 128 (r25-proven) --------
__global__ __launch_bounds__(512) void attn_kernel(const short* __restrict__ Q,
                                                   const short* __restrict__ Kg,
                                                   const short* __restrict__ Vt,
                                                   short* __restrict__ ctx) {
    __shared__ __align__(16) char kvbuf[2][32768];   // per buf: K 16KB | V 16KB
    __shared__ __align__(16) char plds[8][2][2048];  // per-wave 2 x (16x64) P
    int tid = threadIdx.x, w = tid >> 6, l = tid & 63;
    int lhi = l >> 4, llo = l & 15;
    int bh = blockIdx.x & 31, qp = blockIdx.x >> 5;  // qp 0..7
    int b = bh >> 4, h = bh & 15;
    char* pb0 = plds[w][0];
    char* pb1 = plds[w][1];

    const short* Qh = Q + (size_t)bh * S_ * HD_;
    const short* Kh = Kg + (size_t)bh * S_ * HD_;
    const short* Vh = Vt + (size_t)bh * HD_ * S_;

    int qbA = qp, qbB = 15 - qp;
    int NTA = qp + 1;
    const int NT = 17;                               // (qp+1) + (16-qp)

    auto stage = [&](char* buf, int c0) {
#pragma unroll
        for (int i2 = 0; i2 < 2; ++i2) {
            int cc = tid + 512 * i2;                 // 0..1023
            int kr = cc >> 3, ks = (16 * (cc & 7)) ^ ((kr & 7) << 4);
            gl_lds16(Kh + (size_t)(c0 + kr) * HD_ + (ks >> 1), (short*)(buf + cc * 16));
            int vr = cc >> 4, vs = (16 * (cc & 15)) ^ ((vr & 15) << 4);
            gl_lds16(Vh + (size_t)vr * S_ + c0 + (vs >> 1),
                     (short*)(buf + 16384 + cc * 16));
        }
    };

    f32x4 O[4];
#pragma unroll
    for (int n = 0; n < 4; ++n) O[n] = (f32x4){0.f, 0.f, 0.f, 0.f};
    float lpart[4] = {0.f, 0.f, 0.f, 0.f};

    auto writeOut = [&](int qb) {
        int qbs = qb * 128 + w * 16;
#pragma unroll
        for (int j = 0; j < 4; ++j) {
            float ls = lpart[j];
            ls += __shfl_xor(ls, 1);
            ls += __shfl_xor(ls, 2);
            ls += __shfl_xor(ls, 4);
            ls += __shfl_xor(ls, 8);
            float inv = 1.0f / ls;
            int row = qbs + lhi * 4 + j;
            size_t base = ((size_t)(b * S_ + row)) * D_ + h * HD_;
#pragma unroll
            for (int n = 0; n < 4; ++n)
                ctx[base + n * 16 + llo] = f2bf(O[n][j] * inv);
        }
    };

    const float SC = 0.18033688f;                    // 0.125 * log2(e)
    const float M2 = 17.312340f;                     // 12 * log2(e) (fixed max)

    int qbase = qbA * 128 + w * 16;
    short8 aq0 = *(const short8*)(Qh + (size_t)(qbase + llo) * HD_ + 8 * lhi);
    short8 aq1 = *(const short8*)(Qh + (size_t)(qbase + llo) * HD_ + 32 + 8 * lhi);

    stage(kvbuf[0], 0);

    for (int i = 0; i < NT; ++i) {
        asm volatile("s_waitcnt vmcnt(0)" ::: "memory");
        __builtin_amdgcn_s_barrier();
        asm volatile("" ::: "memory");
        int kt = (i < NTA) ? i : i - NTA;
        int c0 = kt * 128;
        if (i + 1 < NT) {
            int ni = i + 1;
            int nkt = (ni < NTA) ? ni : ni - NTA;
            stage(kvbuf[ni & 1], nkt * 128);
        }
        const char* kb = kvbuf[i & 1];
        const char* vb = kb + 16384;

        if (c0 <= qbase + 15) {
            // ---- QK^T: 8 col-blocks of 16 k ----
            f32x4 sc4[8];
#pragma unroll
            for (int cb = 0; cb < 8; ++cb) {
                int row = cb * 16 + llo;
                int sw = (row & 7) << 4;
                short8 kf0 = *(const short8*)(kb + row * 128 + ((16 * lhi) ^ sw));
                short8 kf1 = *(const short8*)(kb + row * 128 + ((64 + 16 * lhi) ^ sw));
                f32x4 z = (f32x4){0.f, 0.f, 0.f, 0.f};
                z = MFMA16(aq0, kf0, z);
                z = MFMA16(aq1, kf1, z);
                sc4[cb] = z;
            }
            // ---- fixed-max softmax, two P half-tiles ----
            bool diag = (c0 + 127 > qbase);          // only the true diagonal tile
#pragma unroll
            for (int j = 0; j < 4; ++j) {
                int qr = qbase + lhi * 4 + j;
                float p[8];
#pragma unroll
                for (int cb = 0; cb < 8; ++cb) {
                    float v = fmaf(sc4[cb][j], SC, -M2);
                    if (diag && (c0 + cb * 16 + llo > qr)) v = -1e30f;
                    p[cb] = fexp2(v);
                }
                lpart[j] += ((p[0] + p[1]) + (p[2] + p[3])) +
                            ((p[4] + p[5]) + (p[6] + p[7]));
                int r = lhi * 4 + j;
                int sw = (r & 7) << 4;
                unsigned pkA = cvt_pk_bf16(p[0], p[1]);
                unsigned pkB = cvt_pk_bf16(p[2], p[3]);
                char* rb = pb0 + r * 128;
                *(short*)(rb + ((2 * llo) ^ sw))      = (short)(pkA);
                *(short*)(rb + ((2 * llo + 32) ^ sw)) = (short)(pkA >> 16);
                *(short*)(rb + ((2 * llo + 64) ^ sw)) = (short)(pkB);
                *(short*)(rb + ((2 * llo + 96) ^ sw)) = (short)(pkB >> 16);
                unsigned pkC = cvt_pk_bf16(p[4], p[5]);
                unsigned pkD = cvt_pk_bf16(p[6], p[7]);
                rb = pb1 + r * 128;
                *(short*)(rb + ((2 * llo) ^ sw))      = (short)(pkC);
                *(short*)(rb + ((2 * llo + 32) ^ sw)) = (short)(pkC >> 16);
                *(short*)(rb + ((2 * llo + 64) ^ sw)) = (short)(pkD);
                *(short*)(rb + ((2 * llo + 96) ^ sw)) = (short)(pkD >> 16);
            }
            // ---- PV: 4 k-chunks of 32 ----
            int swr = (llo & 7) << 4;
            short8 pa[4];
            pa[0] = *(const short8*)(pb0 + llo * 128 + ((16 * lhi) ^ swr));
            pa[1] = *(const short8*)(pb0 + llo * 128 + ((64 + 16 * lhi) ^ swr));
            pa[2] = *(const short8*)(pb1 + llo * 128 + ((16 * lhi) ^ swr));
            pa[3] = *(const short8*)(pb1 + llo * 128 + ((64 + 16 * lhi) ^ swr));
#pragma unroll
            for (int n = 0; n < 4; ++n) {
                int vrow = n * 16 + llo;
                int vsw = (vrow & 15) << 4;
#pragma unroll
                for (int kc = 0; kc < 4; ++kc) {
                    short8 vf = *(const short8*)(vb + vrow * 256 +
                                                 ((kc * 64 + 16 * lhi) ^ vsw));
                    O[n] = MFMA16(pa[kc], vf, O[n]);
                }
            }
        }

        if (i == NTA - 1) {                          // phase A done
            writeOut(qbA);
#pragma unroll
            for (int n = 0; n < 4; ++n) O[n] = (f32x4){0.f, 0.f, 0.f, 0.f};
            lpart[0] = lpart[1] = lpart[2] = lpart[3] = 0.f;
            qbase = qbB * 128 + w * 16;
            aq0 = *(const short8*)(Qh + (size_t)(qbase + llo) * HD_ + 8 * lhi);
            aq1 = *(const short8*)(Qh + (size_t)(qbase + llo) * HD_ + 32 + 8 * lhi);
        }
    }
    writeOut(qbB);
}

extern "C" void kernel_launch(void* const* d_in, const int* in_sizes, int n_in,
                              void* d_out, int out_size, void* d_ws, size_t ws_size,
                              hipStream_t stream) {
    const float* x  = (const float*)d_in[0];
    const float* Wq = (const float*)d_in[1];
    const float* Wk = (const float*)d_in[2];
    const float* Wv = (const float*)d_in[3];
    const float* Wo = (const float*)d_in[4];
    const float* bo = (const float*)d_in[5];
    float* out = (float*)d_out;

    char* ws = (char*)d_ws;
    short* xb    = (short*)(ws);                       // 8 MB (reused as ctx later)
    short* Wqkvt = (short*)(ws + (size_t)(8 << 20));   // 6 MB: [3072][1024] bf16
    short* Wot   = (short*)(ws + (size_t)(14 << 20));  // 2 MB
    short* Qb    = (short*)(ws + (size_t)(16 << 20));  // 8 MB each
    short* Kb    = Qb + (size_t)M_ * D_;
    short* Vtb   = Qb + (size_t)2 * M_ * D_;
    short* ctx   = xb;                                 // alias: xb dead after QKV GEMM

    prep_kernel<<<dim3(32, 32, 5), 256, 0, stream>>>(x, Wq, Wk, Wv, Wo, xb, Wqkvt, Wot);
    gemm_qkv<<<768, 256, 0, stream>>>(xb, Wqkvt, Qb);                      // fused QKV
    attn_kernel<<<256, 512, 0, stream>>>(Qb, Kb, Vtb, ctx);
    gemm_out<<<512, 256, 0, stream>>>(ctx, Wot, bo, out);                  // out-proj
}

// Round 28
// 128.481 us; speedup vs baseline: 1.0665x; 1.0199x over previous
//
#include <hip/hip_runtime.h>
#include <hip/hip_bf16.h>

#define B_  2
#define S_  2048
#define D_  1024
#define H_  16
#define HD_ 64
#define M_  (B_*S_)   // 4096 rows of x

typedef __attribute__((ext_vector_type(8))) short short8;
typedef __attribute__((ext_vector_type(4))) float f32x4;

#define MFMA16(a, b, c) __builtin_amdgcn_mfma_f32_16x16x32_bf16((a), (b), (c), 0, 0, 0)

static __device__ inline short f2bf(float f) {
    union { float f; unsigned u; } v; v.f = f;
    unsigned r = v.u + 0x7FFFu + ((v.u >> 16) & 1u);   // round-to-nearest-even
    return (short)(r >> 16);
}

static __device__ __forceinline__ float fexp2(float x) {   // v_exp_f32 = 2^x
    float r;
    asm volatile("v_exp_f32 %0, %1\n\ts_nop 1" : "=v"(r) : "v"(x));
    return r;
}

static __device__ __forceinline__ unsigned cvt_pk_bf16(float lo, float hi) {
    unsigned r;
    asm volatile("v_cvt_pk_bf16_f32 %0, %1, %2" : "=v"(r) : "v"(lo), "v"(hi));
    return r;
}

static __device__ __forceinline__ void gl_lds16(const short* g, short* l) {
    __builtin_amdgcn_global_load_lds(
        (const __attribute__((address_space(1))) void*)g,
        (__attribute__((address_space(3))) void*)l, 16, 0, 0);
}

// ------- fused prep: z<4 -> transpose W_z to bf16 [N][K]; z==4 -> cvt x ----
__global__ void prep_kernel(const float* __restrict__ x,
                            const float* __restrict__ Wq, const float* __restrict__ Wk,
                            const float* __restrict__ Wv, const float* __restrict__ Wo,
                            short* __restrict__ xb,
                            short* __restrict__ Wqkvt, short* __restrict__ Wot) {
    int z = blockIdx.z;
    if (z == 4) {                                      // x fp32 -> bf16 (4 float4/thread)
        int bid = blockIdx.y * 32 + blockIdx.x;
        int base = bid * 1024 + threadIdx.x;
#pragma unroll
        for (int it = 0; it < 4; ++it) {
            int i = base + it * 256;
            float4 v = ((const float4*)x)[i];
            short4 o;
            o.x = f2bf(v.x); o.y = f2bf(v.y); o.z = f2bf(v.z); o.w = f2bf(v.w);
            ((short4*)xb)[i] = o;
        }
        return;
    }
    __shared__ float tile[32][33];
    const float* W = (z == 0) ? Wq : (z == 1) ? Wk : (z == 2) ? Wv : Wo;
    short* Wt = (z == 3) ? Wot : (Wqkvt + ((size_t)z << 20));
    int t8 = threadIdx.x & 7, ty = threadIdx.x >> 3;   // 8 float4-cols x 32 rows
    int n0 = blockIdx.x * 32, k0 = blockIdx.y * 32;
    float4 v = *(const float4*)&W[(size_t)(k0 + ty) * D_ + n0 + t8 * 4];
    tile[ty][t8 * 4 + 0] = v.x;
    tile[ty][t8 * 4 + 1] = v.y;
    tile[ty][t8 * 4 + 2] = v.z;
    tile[ty][t8 * 4 + 3] = v.w;
    __syncthreads();
    short4 o;
    o.x = f2bf(tile[t8 * 4 + 0][ty]);
    o.y = f2bf(tile[t8 * 4 + 1][ty]);
    o.z = f2bf(tile[t8 * 4 + 2][ty]);
    o.w = f2bf(tile[t8 * 4 + 3][ty]);
    *(short4*)&Wt[(size_t)(n0 + ty) * D_ + k0 + t8 * 4] = o;
}

// ---------------- fused QKV GEMM: 128x128, double-buffered (r14/r18-proven) -
__global__ __launch_bounds__(256) void gemm_qkv(const short* __restrict__ A,
                                                const short* __restrict__ Bt,
                                                short* __restrict__ out) {
    __shared__ __align__(16) short Asm[2][128 * 32];
    __shared__ __align__(16) short Bsm[2][128 * 32];
    const int NBX = 3;                                 // 24 bn-columns / 8 XCDs
    int X = blockIdx.x & 7, t = blockIdx.x >> 3;
    int bm = t / NBX, bn = X * NBX + t % NBX;
    int tid = threadIdx.x, l = tid & 63, w = tid >> 6;
    int lhi = l >> 4, llo = l & 15;
    int wm = w >> 1, wn = w & 1;

    f32x4 acc[4][4];
#pragma unroll
    for (int m = 0; m < 4; ++m)
#pragma unroll
        for (int n = 0; n < 4; ++n) acc[m][n] = (f32x4){0.f, 0.f, 0.f, 0.f};

    const short* Ag = A + (size_t)(bm * 128) * 1024;
    const short* Bg = Bt + (size_t)(bn * 128) * 1024;
    int c0 = tid, c1 = 256 + tid;
    int r0 = ((c0 >> 5) << 3) | (c0 & 7), s0 = ((c0 >> 3) & 3) ^ (r0 & 3);
    int r1 = ((c1 >> 5) << 3) | (c1 & 7), s1 = ((c1 >> 3) & 3) ^ (r1 & 3);

    auto stage = [&](int buf, int k0) {
        gl_lds16(Ag + (size_t)r0 * 1024 + k0 + s0 * 8, &Asm[buf][c0 * 8]);
        gl_lds16(Ag + (size_t)r1 * 1024 + k0 + s1 * 8, &Asm[buf][c1 * 8]);
        gl_lds16(Bg + (size_t)r0 * 1024 + k0 + s0 * 8, &Bsm[buf][c0 * 8]);
        gl_lds16(Bg + (size_t)r1 * 1024 + k0 + s1 * 8, &Bsm[buf][c1 * 8]);
    };

    int cia[4], cib[4];
#pragma unroll
    for (int m = 0; m < 4; ++m) {
        int row = wm * 64 + m * 16 + llo;
        cia[m] = ((row >> 3) << 5) | (((lhi ^ row) & 3) << 3) | (row & 7);
    }
#pragma unroll
    for (int n = 0; n < 4; ++n) {
        int row = wn * 64 + n * 16 + llo;
        cib[n] = ((row >> 3) << 5) | (((lhi ^ row) & 3) << 3) | (row & 7);
    }

    stage(0, 0);
    for (int i = 0; i < 32; ++i) {
        asm volatile("s_waitcnt vmcnt(0)" ::: "memory");
        __builtin_amdgcn_s_barrier();
        asm volatile("" ::: "memory");
        if (i + 1 < 32) stage((i + 1) & 1, (i + 1) * 32);
        int cur = i & 1;
        short8 af[4], bf[4];
#pragma unroll
        for (int m = 0; m < 4; ++m) af[m] = *(const short8*)&Asm[cur][cia[m] * 8];
#pragma unroll
        for (int n = 0; n < 4; ++n) bf[n] = *(const short8*)&Bsm[cur][cib[n] * 8];
#pragma unroll
        for (int m = 0; m < 4; ++m)
#pragma unroll
            for (int n = 0; n < 4; ++n)
                acc[m][n] = MFMA16(af[m], bf[n], acc[m][n]);
    }

    int rowb = bm * 128 + wm * 64, colb = bn * 128 + wn * 64;
#pragma unroll
    for (int m = 0; m < 4; ++m) {
#pragma unroll
        for (int n = 0; n < 4; ++n) {
            int col = colb + n * 16 + llo;
#pragma unroll
            for (int j = 0; j < 4; ++j) {
                int row = rowb + m * 16 + lhi * 4 + j;
                float v = acc[m][n][j];
                int proj = col >> 10, n1 = col & 1023;
                int h = n1 >> 6, hd = n1 & 63;
                int b = row >> 11, s = row & 2047;
                size_t off;
                if (proj == 0)
                    off = ((size_t)(b * 16 + h) * 2048 + s) * 64 + hd;
                else if (proj == 1)
                    off = (size_t)M_ * D_ + ((size_t)(b * 16 + h) * 2048 + s) * 64 + hd;
                else
                    off = (size_t)2 * M_ * D_ + ((size_t)(b * 16 + h) * 64 + hd) * 2048 + s;
                out[off] = f2bf(v);
            }
        }
    }
}

// ---------------- out-proj GEMM: 64x128, double-buffered (r16-proven) ------
__global__ __launch_bounds__(256, 6) void gemm_out(const short* __restrict__ A,
                                                   const short* __restrict__ Bt,
                                                   const float* __restrict__ bias,
                                                   float* __restrict__ out) {
    __shared__ __align__(16) short Asm[2][64 * 32];
    __shared__ __align__(16) short Bsm[2][128 * 32];
    int bn = blockIdx.x & 7, bm = blockIdx.x >> 3;
    int tid = threadIdx.x, l = tid & 63, w = tid >> 6;
    int lhi = l >> 4, llo = l & 15;

    f32x4 acc[4][2];
#pragma unroll
    for (int m = 0; m < 4; ++m)
#pragma unroll
        for (int n = 0; n < 2; ++n) acc[m][n] = (f32x4){0.f, 0.f, 0.f, 0.f};

    const short* Ag = A + (size_t)(bm * 64) * 1024;
    const short* Bg = Bt + (size_t)(bn * 128) * 1024;
    int ca = tid;
    int ra = ((ca >> 5) << 3) | (ca & 7), sa = ((ca >> 3) & 3) ^ (ra & 3);
    int cb0 = tid, cb1 = tid + 256;
    int rb0 = ((cb0 >> 5) << 3) | (cb0 & 7), sb0 = ((cb0 >> 3) & 3) ^ (rb0 & 3);
    int rb1 = ((cb1 >> 5) << 3) | (cb1 & 7), sb1 = ((cb1 >> 3) & 3) ^ (rb1 & 3);

    auto stage = [&](int buf, int k0) {
        gl_lds16(Ag + (size_t)ra * 1024 + k0 + sa * 8, &Asm[buf][ca * 8]);
        gl_lds16(Bg + (size_t)rb0 * 1024 + k0 + sb0 * 8, &Bsm[buf][cb0 * 8]);
        gl_lds16(Bg + (size_t)rb1 * 1024 + k0 + sb1 * 8, &Bsm[buf][cb1 * 8]);
    };

    int cia[4], cib[2];
#pragma unroll
    for (int m = 0; m < 4; ++m) {
        int row = m * 16 + llo;
        cia[m] = ((row >> 3) << 5) | (((lhi ^ row) & 3) << 3) | (row & 7);
    }
#pragma unroll
    for (int n = 0; n < 2; ++n) {
        int row = w * 32 + n * 16 + llo;
        cib[n] = ((row >> 3) << 5) | (((lhi ^ row) & 3) << 3) | (row & 7);
    }

    stage(0, 0);
    for (int i = 0; i < 32; ++i) {
        asm volatile("s_waitcnt vmcnt(0)" ::: "memory");
        __builtin_amdgcn_s_barrier();
        asm volatile("" ::: "memory");
        if (i + 1 < 32) stage((i + 1) & 1, (i + 1) * 32);
        int cur = i & 1;
        short8 af[4], bf[2];
#pragma unroll
        for (int m = 0; m < 4; ++m) af[m] = *(const short8*)&Asm[cur][cia[m] * 8];
#pragma unroll
        for (int n = 0; n < 2; ++n) bf[n] = *(const short8*)&Bsm[cur][cib[n] * 8];
#pragma unroll
        for (int m = 0; m < 4; ++m)
#pragma unroll
            for (int n = 0; n < 2; ++n)
                acc[m][n] = MFMA16(af[m], bf[n], acc[m][n]);
    }

    int rowb = bm * 64, colb = bn * 128 + w * 32;
#pragma unroll
    for (int m = 0; m < 4; ++m)
#pragma unroll
        for (int n = 0; n < 2; ++n) {
            int col = colb + n * 16 + llo;
#pragma unroll
            for (int j = 0; j < 4; ++j) {
                int row = rowb + m * 16 + lhi * 4 + j;
                out[(size_t)row * 1024 + col] = acc[m][n][j] + bias[col];
            }
        }
}

// ---------------- causal flash attention, k-tile = 256 ---------------------
// Block = 8 waves x 16 q-rows = one 128-row Q-block; grid 256 = (bh, qp).
// Pairing (qp, 15-qp): tiles = ((qp>>1)+1) + (((15-qp)>>1)+1) = 9, uniform.
// Per tile, the r25-proven 128-col body runs twice (half ch=0,1 at
// ccol = c0 + ch*128); halves above the diagonal are skipped.
// K tile [256][64] (128B rows, swizzle (row&7)<<4, as proven).
// V^T tile [64][256] (512B rows, involution (vrow&31)<<4, 2-way reads).
// LDS: kvbuf 2 x (K 32KB | V 32KB) = 128KB + plds 32KB = 160KB (1 block/CU).
__global__ __launch_bounds__(512) void attn_kernel(const short* __restrict__ Q,
                                                   const short* __restrict__ Kg,
                                                   const short* __restrict__ Vt,
                                                   short* __restrict__ ctx) {
    __shared__ __align__(16) char kvbuf[2][65536];   // per buf: K 32KB | V 32KB
    __shared__ __align__(16) char plds[8][2][2048];  // per-wave 2 x (16x64) P
    int tid = threadIdx.x, w = tid >> 6, l = tid & 63;
    int lhi = l >> 4, llo = l & 15;
    int bh = blockIdx.x & 31, qp = blockIdx.x >> 5;  // qp 0..7
    int b = bh >> 4, h = bh & 15;
    char* pb0 = plds[w][0];
    char* pb1 = plds[w][1];

    const short* Qh = Q + (size_t)bh * S_ * HD_;
    const short* Kh = Kg + (size_t)bh * S_ * HD_;
    const short* Vh = Vt + (size_t)bh * HD_ * S_;

    int qbA = qp, qbB = 15 - qp;
    int NTA = (qbA >> 1) + 1;
    const int NT = 9;

    // staging: 512 thr x (4 K-chunks + 4 V-chunks) of 16B = 32KB + 32KB
    auto stage = [&](char* buf, int c0) {
#pragma unroll
        for (int i2 = 0; i2 < 4; ++i2) {
            int cc = tid + 512 * i2;                 // 0..2047
            int kr = cc >> 3, ks = (16 * (cc & 7)) ^ ((kr & 7) << 4);
            gl_lds16(Kh + (size_t)(c0 + kr) * HD_ + (ks >> 1), (short*)(buf + cc * 16));
            int vr = cc >> 5, vs = (16 * (cc & 31)) ^ ((vr & 31) << 4);
            gl_lds16(Vh + (size_t)vr * S_ + c0 + (vs >> 1),
                     (short*)(buf + 32768 + cc * 16));
        }
    };

    f32x4 O[4];
#pragma unroll
    for (int n = 0; n < 4; ++n) O[n] = (f32x4){0.f, 0.f, 0.f, 0.f};
    float lpart[4] = {0.f, 0.f, 0.f, 0.f};

    auto writeOut = [&](int qb) {
        int qbs = qb * 128 + w * 16;
#pragma unroll
        for (int j = 0; j < 4; ++j) {
            float ls = lpart[j];
            ls += __shfl_xor(ls, 1);
            ls += __shfl_xor(ls, 2);
            ls += __shfl_xor(ls, 4);
            ls += __shfl_xor(ls, 8);
            float inv = 1.0f / ls;
            int row = qbs + lhi * 4 + j;
            size_t base = ((size_t)(b * S_ + row)) * D_ + h * HD_;
#pragma unroll
            for (int n = 0; n < 4; ++n)
                ctx[base + n * 16 + llo] = f2bf(O[n][j] * inv);
        }
    };

    const float SC = 0.18033688f;                    // 0.125 * log2(e)
    const float M2 = 17.312340f;                     // 12 * log2(e) (fixed max)

    int qbase = qbA * 128 + w * 16;
    short8 aq0 = *(const short8*)(Qh + (size_t)(qbase + llo) * HD_ + 8 * lhi);
    short8 aq1 = *(const short8*)(Qh + (size_t)(qbase + llo) * HD_ + 32 + 8 * lhi);

    stage(kvbuf[0], 0);

    for (int i = 0; i < NT; ++i) {
        asm volatile("s_waitcnt vmcnt(0)" ::: "memory");
        __builtin_amdgcn_s_barrier();
        asm volatile("" ::: "memory");
        int kt = (i < NTA) ? i : i - NTA;
        int c0 = kt * 256;
        if (i + 1 < NT) {
            int ni = i + 1;
            int nkt = (ni < NTA) ? ni : ni - NTA;
            stage(kvbuf[ni & 1], nkt * 256);
        }
        const char* kb = kvbuf[i & 1];
        const char* vb = kb + 32768;

#pragma unroll
        for (int ch = 0; ch < 2; ++ch) {
            int ccol = c0 + ch * 128;
            if (ccol <= qbase + 15) {
                // ---- QK^T: 8 col-blocks of 16 k ----
                f32x4 sc4[8];
#pragma unroll
                for (int cb = 0; cb < 8; ++cb) {
                    int row = ch * 128 + cb * 16 + llo;
                    int sw = (row & 7) << 4;
                    short8 kf0 = *(const short8*)(kb + row * 128 + ((16 * lhi) ^ sw));
                    short8 kf1 = *(const short8*)(kb + row * 128 + ((64 + 16 * lhi) ^ sw));
                    f32x4 z = (f32x4){0.f, 0.f, 0.f, 0.f};
                    z = MFMA16(aq0, kf0, z);
                    z = MFMA16(aq1, kf1, z);
                    sc4[cb] = z;
                }
                // ---- fixed-max softmax, two P half-tiles ----
                bool diag = (ccol + 127 > qbase);
#pragma unroll
                for (int j = 0; j < 4; ++j) {
                    int qr = qbase + lhi * 4 + j;
                    float p[8];
#pragma unroll
                    for (int cb = 0; cb < 8; ++cb) {
                        float v = fmaf(sc4[cb][j], SC, -M2);
                        if (diag && (ccol + cb * 16 + llo > qr)) v = -1e30f;
                        p[cb] = fexp2(v);
                    }
                    lpart[j] += ((p[0] + p[1]) + (p[2] + p[3])) +
                                ((p[4] + p[5]) + (p[6] + p[7]));
                    int r = lhi * 4 + j;
                    int sw = (r & 7) << 4;
                    unsigned pkA = cvt_pk_bf16(p[0], p[1]);
                    unsigned pkB = cvt_pk_bf16(p[2], p[3]);
                    char* rb = pb0 + r * 128;
                    *(short*)(rb + ((2 * llo) ^ sw))      = (short)(pkA);
                    *(short*)(rb + ((2 * llo + 32) ^ sw)) = (short)(pkA >> 16);
                    *(short*)(rb + ((2 * llo + 64) ^ sw)) = (short)(pkB);
                    *(short*)(rb + ((2 * llo + 96) ^ sw)) = (short)(pkB >> 16);
                    unsigned pkC = cvt_pk_bf16(p[4], p[5]);
                    unsigned pkD = cvt_pk_bf16(p[6], p[7]);
                    rb = pb1 + r * 128;
                    *(short*)(rb + ((2 * llo) ^ sw))      = (short)(pkC);
                    *(short*)(rb + ((2 * llo + 32) ^ sw)) = (short)(pkC >> 16);
                    *(short*)(rb + ((2 * llo + 64) ^ sw)) = (short)(pkD);
                    *(short*)(rb + ((2 * llo + 96) ^ sw)) = (short)(pkD >> 16);
                }
                // ---- PV: 4 k-chunks of 32 within this half ----
                int swr = (llo & 7) << 4;
                short8 pa[4];
                pa[0] = *(const short8*)(pb0 + llo * 128 + ((16 * lhi) ^ swr));
                pa[1] = *(const short8*)(pb0 + llo * 128 + ((64 + 16 * lhi) ^ swr));
                pa[2] = *(const short8*)(pb1 + llo * 128 + ((16 * lhi) ^ swr));
                pa[3] = *(const short8*)(pb1 + llo * 128 + ((64 + 16 * lhi) ^ swr));
#pragma unroll
                for (int n = 0; n < 4; ++n) {
                    int vrow = n * 16 + llo;
#pragma unroll
                    for (int kc = 0; kc < 4; ++kc) {
                        int slot = ch * 16 + kc * 4 + lhi;            // 16B slot in 512B row
                        short8 vf = *(const short8*)(vb + vrow * 512 +
                                                     ((slot ^ (vrow & 31)) * 16));
                        O[n] = MFMA16(pa[kc], vf, O[n]);
                    }
                }
            }
        }

        if (i == NTA - 1) {                          // phase A done
            writeOut(qbA);
#pragma unroll
            for (int n = 0; n < 4; ++n) O[n] = (f32x4){0.f, 0.f, 0.f, 0.f};
            lpart[0] = lpart[1] = lpart[2] = lpart[3] = 0.f;
            qbase = qbB * 128 + w * 16;
            aq0 = *(const short8*)(Qh + (size_t)(qbase + llo) * HD_ + 8 * lhi);
            aq1 = *(const short8*)(Qh + (size_t)(qbase + llo) * HD_ + 32 + 8 * lhi);
        }
    }
    writeOut(qbB);
}

extern "C" void kernel_launch(void* const* d_in, const int* in_sizes, int n_in,
                              void* d_out, int out_size, void* d_ws, size_t ws_size,
                              hipStream_t stream) {
    const float* x  = (const float*)d_in[0];
    const float* Wq = (const float*)d_in[1];
    const float* Wk = (const float*)d_in[2];
    const float* Wv = (const float*)d_in[3];
    const float* Wo = (const float*)d_in[4];
    const float* bo = (const float*)d_in[5];
    float* out = (float*)d_out;

    char* ws = (char*)d_ws;
    short* xb    = (short*)(ws);                       // 8 MB (reused as ctx later)
    short* Wqkvt = (short*)(ws + (size_t)(8 << 20));   // 6 MB: [3072][1024] bf16
    short* Wot   = (short*)(ws + (size_t)(14 << 20));  // 2 MB
    short* Qb    = (short*)(ws + (size_t)(16 << 20));  // 8 MB each
    short* Kb    = Qb + (size_t)M_ * D_;
    short* Vtb   = Qb + (size_t)2 * M_ * D_;
    short* ctx   = xb;                                 // alias: xb dead after QKV GEMM

    prep_kernel<<<dim3(32, 32, 5), 256, 0, stream>>>(x, Wq, Wk, Wv, Wo, xb, Wqkvt, Wot);
    gemm_qkv<<<768, 256, 0, stream>>>(xb, Wqkvt, Qb);                      // fused QKV
    attn_kernel<<<256, 512, 0, stream>>>(Qb, Kb, Vtb, ctx);
    gemm_out<<<512, 256, 0, stream>>>(ctx, Wot, bo, out);                  // out-proj
}